// Round 1
// baseline (8190.866 us; speedup 1.0000x reference)
//
#include <hip/hip_runtime.h>
#include <math.h>

#define BB 8
#define NN 1000
#define CC 81
#define NC 80                     // foreground classes
#define IMG_W_M1 1332.0f
#define IMG_H_M1 799.0f
#define SCORE_THRESH 0.05f
#define NMS_THRESH 0.5f
#define DETS 100
#define CAP 8192                  // per-image candidate capacity after NMS
#define DW_CLIP 4.135166556742356f  // log(1000/16) rounded to f32

// ws layout (bytes):
//   [0,      32000)  rowmax  f32[8000]
//   [32000,  64000)  rowsum  f32[8000]
//   [64000,  64032)  counters u32[8]
//   [64128,  64128 + 8*CAP*6*4)  candidates: per image, CAP x {score, x1,y1,x2,y2, flatidx(int)}

__global__ __launch_bounds__(256) void softmax_stats(
    const float* __restrict__ logits, float* __restrict__ rowmax,
    float* __restrict__ rowsum, unsigned* __restrict__ counters) {
  int r = blockIdx.x * 256 + threadIdx.x;
  if (blockIdx.x == 0 && threadIdx.x < BB) counters[threadIdx.x] = 0u;
  if (r >= BB * NN) return;
  const float* l = logits + (size_t)r * CC;
  float m = l[0];
  for (int c = 1; c < CC; ++c) m = fmaxf(m, l[c]);
  float s = 0.0f;
  for (int c = 0; c < CC; ++c) s += expf(l[c] - m);
  rowmax[r] = m;
  rowsum[r] = s;
}

__global__ __launch_bounds__(256) void per_class_nms(
    const float* __restrict__ logits, const float* __restrict__ reg,
    const float* __restrict__ props, const float* __restrict__ rowmax,
    const float* __restrict__ rowsum, unsigned* __restrict__ counters,
    float* __restrict__ cand) {
#pragma clang fp contract(off)
  __shared__ float s_score[NN];
  __shared__ int   s_idx[NN];
  __shared__ float s_sscore[NN];
  __shared__ int   s_sidx[NN];
  __shared__ float s_box[NN * 4];
  __shared__ unsigned char s_keep[NN];
  __shared__ int s_cnt;

  const int img = blockIdx.x / NC;
  const int cls = blockIdx.x % NC + 1;   // foreground class id 1..80
  const int t = threadIdx.x;

  if (t == 0) s_cnt = 0;
  __syncthreads();

  // Phase 1: collect candidates with prob > thresh
  for (int r = t; r < NN; r += 256) {
    int row = img * NN + r;
    float e = expf(logits[(size_t)row * CC + cls] - rowmax[row]);
    float p = e / rowsum[row];          // matches exp(x-max)/sum elementwise div
    if (p > SCORE_THRESH) {
      int pos = atomicAdd(&s_cnt, 1);
      s_score[pos] = p;
      s_idx[pos] = r;
    }
  }
  __syncthreads();
  const int n = s_cnt;

  // Phase 2: rank sort by (score desc, original row asc) == stable argsort(-scores)
  for (int i = t; i < n; i += 256) {
    float si = s_score[i];
    int   ii = s_idx[i];
    int rank = 0;
    for (int j = 0; j < n; ++j) {
      float sj = s_score[j];
      rank += (sj > si) || (sj == si && s_idx[j] < ii);
    }
    s_sscore[rank] = si;
    s_sidx[rank] = ii;
  }
  __syncthreads();

  // Phase 3: decode + clip boxes for sorted candidates (BoxCoder.decode, TO_REMOVE=1)
  for (int i = t; i < n; i += 256) {
    int r = s_sidx[i];
    int row = img * NN + r;
    float x1 = props[row * 4 + 0], y1 = props[row * 4 + 1];
    float x2 = props[row * 4 + 2], y2 = props[row * 4 + 3];
    float w = x2 - x1 + 1.0f, h = y2 - y1 + 1.0f;
    float cx = x1 + 0.5f * w,  cy = y1 + 0.5f * h;
    const float* rg = reg + (size_t)row * (CC * 4) + cls * 4;
    float dx = rg[0] / 10.0f, dy = rg[1] / 10.0f;
    float dw = fminf(rg[2] / 5.0f, DW_CLIP);
    float dh = fminf(rg[3] / 5.0f, DW_CLIP);
    float pcx = dx * w + cx, pcy = dy * h + cy;
    float pw = expf(dw) * w, ph = expf(dh) * h;
    float bx1 = pcx - 0.5f * pw;
    float by1 = pcy - 0.5f * ph;
    float bx2 = pcx + 0.5f * pw - 1.0f;
    float by2 = pcy + 0.5f * ph - 1.0f;
    bx1 = fminf(fmaxf(bx1, 0.0f), IMG_W_M1);
    bx2 = fminf(fmaxf(bx2, 0.0f), IMG_W_M1);
    by1 = fminf(fmaxf(by1, 0.0f), IMG_H_M1);
    by2 = fminf(fmaxf(by2, 0.0f), IMG_H_M1);
    s_box[i * 4 + 0] = bx1;
    s_box[i * 4 + 1] = by1;
    s_box[i * 4 + 2] = bx2;
    s_box[i * 4 + 3] = by2;
    s_keep[i] = 1;
  }
  __syncthreads();

  // Phase 4: greedy NMS (torchvision IoU, no +1), identical to reference semantics
  for (int i = 0; i < n; ++i) {
    if (s_keep[i]) {   // uniform branch: all threads read same LDS value
      float ax1 = s_box[i * 4 + 0], ay1 = s_box[i * 4 + 1];
      float ax2 = s_box[i * 4 + 2], ay2 = s_box[i * 4 + 3];
      float areaA = (ax2 - ax1) * (ay2 - ay1);
      for (int j = i + 1 + t; j < n; j += 256) {
        if (!s_keep[j]) continue;
        float bx1 = s_box[j * 4 + 0], by1 = s_box[j * 4 + 1];
        float bx2 = s_box[j * 4 + 2], by2 = s_box[j * 4 + 3];
        float areaB = (bx2 - bx1) * (by2 - by1);
        float wx = fmaxf(fminf(ax2, bx2) - fmaxf(ax1, bx1), 0.0f);
        float wy = fmaxf(fminf(ay2, by2) - fmaxf(ay1, by1), 0.0f);
        float inter = wx * wy;
        float iou = inter / ((areaA + areaB) - inter + 1e-9f);
        if (iou > NMS_THRESH) s_keep[j] = 0;
      }
    }
    __syncthreads();
  }

  // Phase 5: emit survivors to per-image global list
  for (int i = t; i < n; i += 256) {
    if (s_keep[i]) {
      unsigned pos = atomicAdd(&counters[img], 1u);
      if (pos < CAP) {
        float* c = cand + ((size_t)img * CAP + pos) * 6;
        c[0] = s_sscore[i];
        c[1] = s_box[i * 4 + 0];
        c[2] = s_box[i * 4 + 1];
        c[3] = s_box[i * 4 + 2];
        c[4] = s_box[i * 4 + 3];
        ((int*)c)[5] = (cls - 1) * NN + s_sidx[i];   // flat idx for tie-break + label
      }
    }
  }
}

__global__ __launch_bounds__(256) void topk_out(
    const unsigned* __restrict__ counters, const float* __restrict__ cand,
    float* __restrict__ dets_out, float* __restrict__ labels_out) {
#pragma clang fp contract(off)
  __shared__ float s_sc[CAP];
  __shared__ int   s_fl[CAP];
  const int img = blockIdx.x;
  const int t = threadIdx.x;
  int n = (int)counters[img];
  if (n > CAP) n = CAP;
  const float* cbase = cand + (size_t)img * CAP * 6;

  for (int i = t; i < n; i += 256) {
    s_sc[i] = cbase[i * 6];
    s_fl[i] = ((const int*)cbase)[i * 6 + 5];
  }
  // Prefill: slots beyond kept count -> zero box/score, label -1 (matches topv==0 path)
  for (int k = t; k < DETS; k += 256) {
    float* d = dets_out + (size_t)(img * DETS + k) * 5;
    d[0] = 0.0f; d[1] = 0.0f; d[2] = 0.0f; d[3] = 0.0f; d[4] = 0.0f;
    labels_out[img * DETS + k] = -1.0f;
  }
  __syncthreads();

  // Rank-based top-100: tie-break by lower flat index (lax.top_k semantics)
  for (int i = t; i < n; i += 256) {
    float si = s_sc[i];
    int   fi = s_fl[i];
    int rank = 0;
    for (int j = 0; j < n && rank < DETS; ++j) {
      float sj = s_sc[j];
      rank += (sj > si) || (sj == si && s_fl[j] < fi);
    }
    if (rank < DETS) {
      float* d = dets_out + (size_t)(img * DETS + rank) * 5;
      d[0] = cbase[i * 6 + 1];
      d[1] = cbase[i * 6 + 2];
      d[2] = cbase[i * 6 + 3];
      d[3] = cbase[i * 6 + 4];
      d[4] = si;
      labels_out[img * DETS + rank] = (float)(fi / NN + 1);
    }
  }
}

extern "C" void kernel_launch(void* const* d_in, const int* in_sizes, int n_in,
                              void* d_out, int out_size, void* d_ws, size_t ws_size,
                              hipStream_t stream) {
  const float* logits = (const float*)d_in[0];   // [8000, 81]
  const float* reg    = (const float*)d_in[1];   // [8000, 324]
  const float* props  = (const float*)d_in[2];   // [8000, 4]
  // d_in[3] = features, unused (OUTPUT_FEATURE=False)

  float* out = (float*)d_out;                    // dets [8,100,5] then labels [8,100]
  char* ws = (char*)d_ws;
  float*    rowmax   = (float*)(ws);
  float*    rowsum   = (float*)(ws + 32000);
  unsigned* counters = (unsigned*)(ws + 64000);
  float*    cand     = (float*)(ws + 64128);

  softmax_stats<<<(BB * NN + 255) / 256, 256, 0, stream>>>(logits, rowmax, rowsum, counters);
  per_class_nms<<<BB * NC, 256, 0, stream>>>(logits, reg, props, rowmax, rowsum, counters, cand);
  topk_out<<<BB, 256, 0, stream>>>(counters, cand, out, out + BB * DETS * 5);
}

// Round 2
// 740.761 us; speedup vs baseline: 11.0574x; 11.0574x over previous
//
#include <hip/hip_runtime.h>
#include <math.h>

#define BB 8
#define NN 1000
#define CC 81
#define NC 80                     // foreground classes
#define IMG_W_M1 1332.0f
#define IMG_H_M1 799.0f
#define SCORE_THRESH 0.05f
#define NMS_THRESH 0.5f
#define DETS 100
#define CAP 8192                  // per-image candidate capacity after NMS
#define DW_CLIP 4.135166556742356f  // log(1000/16) rounded to f32

// ws layout (bytes):
//   [0,      32000)  rowmax  f32[8000]
//   [32000,  64000)  rowsum  f32[8000]
//   [64000,  64032)  counters u32[8]
//   [64128,  64128 + 8*CAP*6*4)  candidates: per image, CAP x {score, x1,y1,x2,y2, flatidx(int)}

__global__ __launch_bounds__(256) void softmax_stats(
    const float* __restrict__ logits, float* __restrict__ rowmax,
    float* __restrict__ rowsum, unsigned* __restrict__ counters) {
  int r = blockIdx.x * 256 + threadIdx.x;
  if (blockIdx.x == 0 && threadIdx.x < BB) counters[threadIdx.x] = 0u;
  if (r >= BB * NN) return;
  const float* l = logits + (size_t)r * CC;
  float m = l[0];
  for (int c = 1; c < CC; ++c) m = fmaxf(m, l[c]);
  float s = 0.0f;
  for (int c = 0; c < CC; ++c) s += expf(l[c] - m);
  rowmax[r] = m;
  rowsum[r] = s;
}

__global__ __launch_bounds__(256) void per_class_nms(
    const float* __restrict__ logits, const float* __restrict__ reg,
    const float* __restrict__ props, const float* __restrict__ rowmax,
    const float* __restrict__ rowsum, unsigned* __restrict__ counters,
    float* __restrict__ cand) {
#pragma clang fp contract(off)
  __shared__ float s_score[NN];
  __shared__ int   s_idx[NN];
  __shared__ float s_sscore[NN];
  __shared__ int   s_sidx[NN];
  __shared__ float s_box[NN * 4];
  __shared__ unsigned char s_keep[NN];
  __shared__ int s_cnt;

  const int img = blockIdx.x / NC;
  const int cls = blockIdx.x % NC + 1;   // foreground class id 1..80
  const int t = threadIdx.x;

  if (t == 0) s_cnt = 0;
  __syncthreads();

  // Phase 1: collect candidates with prob > thresh
  for (int r = t; r < NN; r += 256) {
    int row = img * NN + r;
    float e = expf(logits[(size_t)row * CC + cls] - rowmax[row]);
    float p = e / rowsum[row];          // matches exp(x-max)/sum elementwise div
    if (p > SCORE_THRESH) {
      int pos = atomicAdd(&s_cnt, 1);
      s_score[pos] = p;
      s_idx[pos] = r;
    }
  }
  __syncthreads();
  const int n = s_cnt;

  // Phase 2: rank sort by (score desc, original row asc) == stable argsort(-scores)
  // Fixed trip count, non-short-circuit: lets the compiler unroll + pipeline ds_reads.
  for (int i = t; i < n; i += 256) {
    float si = s_score[i];
    int   ii = s_idx[i];
    int rank = 0;
#pragma unroll 8
    for (int j = 0; j < n; ++j) {
      float sj = s_score[j];
      rank += (int)((sj > si) | ((sj == si) & (s_idx[j] < ii)));
    }
    s_sscore[rank] = si;
    s_sidx[rank] = ii;
  }
  __syncthreads();

  // Phase 3: decode + clip boxes for sorted candidates (BoxCoder.decode, TO_REMOVE=1)
  for (int i = t; i < n; i += 256) {
    int r = s_sidx[i];
    int row = img * NN + r;
    float x1 = props[row * 4 + 0], y1 = props[row * 4 + 1];
    float x2 = props[row * 4 + 2], y2 = props[row * 4 + 3];
    float w = x2 - x1 + 1.0f, h = y2 - y1 + 1.0f;
    float cx = x1 + 0.5f * w,  cy = y1 + 0.5f * h;
    const float* rg = reg + (size_t)row * (CC * 4) + cls * 4;
    float dx = rg[0] / 10.0f, dy = rg[1] / 10.0f;
    float dw = fminf(rg[2] / 5.0f, DW_CLIP);
    float dh = fminf(rg[3] / 5.0f, DW_CLIP);
    float pcx = dx * w + cx, pcy = dy * h + cy;
    float pw = expf(dw) * w, ph = expf(dh) * h;
    float bx1 = pcx - 0.5f * pw;
    float by1 = pcy - 0.5f * ph;
    float bx2 = pcx + 0.5f * pw - 1.0f;
    float by2 = pcy + 0.5f * ph - 1.0f;
    bx1 = fminf(fmaxf(bx1, 0.0f), IMG_W_M1);
    bx2 = fminf(fmaxf(bx2, 0.0f), IMG_W_M1);
    by1 = fminf(fmaxf(by1, 0.0f), IMG_H_M1);
    by2 = fminf(fmaxf(by2, 0.0f), IMG_H_M1);
    s_box[i * 4 + 0] = bx1;
    s_box[i * 4 + 1] = by1;
    s_box[i * 4 + 2] = bx2;
    s_box[i * 4 + 3] = by2;
    s_keep[i] = 1;
  }
  __syncthreads();

  // Phase 4: greedy NMS (torchvision IoU, no +1), identical to reference semantics
  for (int i = 0; i < n; ++i) {
    if (s_keep[i]) {   // uniform branch: all threads read same LDS value
      float ax1 = s_box[i * 4 + 0], ay1 = s_box[i * 4 + 1];
      float ax2 = s_box[i * 4 + 2], ay2 = s_box[i * 4 + 3];
      float areaA = (ax2 - ax1) * (ay2 - ay1);
      for (int j = i + 1 + t; j < n; j += 256) {
        if (!s_keep[j]) continue;
        float bx1 = s_box[j * 4 + 0], by1 = s_box[j * 4 + 1];
        float bx2 = s_box[j * 4 + 2], by2 = s_box[j * 4 + 3];
        float areaB = (bx2 - bx1) * (by2 - by1);
        float wx = fmaxf(fminf(ax2, bx2) - fmaxf(ax1, bx1), 0.0f);
        float wy = fmaxf(fminf(ay2, by2) - fmaxf(ay1, by1), 0.0f);
        float inter = wx * wy;
        float iou = inter / ((areaA + areaB) - inter + 1e-9f);
        if (iou > NMS_THRESH) s_keep[j] = 0;
      }
    }
    __syncthreads();
  }

  // Phase 5: emit survivors to per-image global list
  for (int i = t; i < n; i += 256) {
    if (s_keep[i]) {
      unsigned pos = atomicAdd(&counters[img], 1u);
      if (pos < CAP) {
        float* c = cand + ((size_t)img * CAP + pos) * 6;
        c[0] = s_sscore[i];
        c[1] = s_box[i * 4 + 0];
        c[2] = s_box[i * 4 + 1];
        c[3] = s_box[i * 4 + 2];
        c[4] = s_box[i * 4 + 3];
        ((int*)c)[5] = (cls - 1) * NN + s_sidx[i];   // flat idx for tie-break + label
      }
    }
  }
}

#define TK_THREADS 1024

__global__ __launch_bounds__(TK_THREADS) void topk_out(
    const unsigned* __restrict__ counters, const float* __restrict__ cand,
    float* __restrict__ dets_out, float* __restrict__ labels_out) {
#pragma clang fp contract(off)
  __shared__ float s_sc[CAP];
  __shared__ int   s_fl[CAP];
  const int img = blockIdx.x;
  const int t = threadIdx.x;
  int n = (int)counters[img];
  if (n > CAP) n = CAP;
  const float* cbase = cand + (size_t)img * CAP * 6;

  for (int i = t; i < n; i += TK_THREADS) {
    s_sc[i] = cbase[i * 6];
    s_fl[i] = ((const int*)cbase)[i * 6 + 5];
  }
  // Prefill: slots beyond kept count -> zero box/score, label -1 (matches topv==0 path)
  for (int k = t; k < DETS; k += TK_THREADS) {
    float* d = dets_out + (size_t)(img * DETS + k) * 5;
    d[0] = 0.0f; d[1] = 0.0f; d[2] = 0.0f; d[3] = 0.0f; d[4] = 0.0f;
    labels_out[img * DETS + k] = -1.0f;
  }
  __syncthreads();

  // Rank-based top-100: tie-break by lower flat index (lax.top_k semantics).
  // FIXED trip count (no early exit): a data-dependent exit serializes the loop
  // on ds_read latency (~120 cyc/iter) -- that was 8 ms in R1. Fixed-trip +
  // unroll lets the compiler pipeline the LDS broadcasts.
  for (int i = t; i < n; i += TK_THREADS) {
    float si = s_sc[i];
    int   fi = s_fl[i];
    int rank = 0;
#pragma unroll 8
    for (int j = 0; j < n; ++j) {
      float sj = s_sc[j];
      rank += (int)((sj > si) | ((sj == si) & (s_fl[j] < fi)));
    }
    if (rank < DETS) {
      float* d = dets_out + (size_t)(img * DETS + rank) * 5;
      d[0] = cbase[i * 6 + 1];
      d[1] = cbase[i * 6 + 2];
      d[2] = cbase[i * 6 + 3];
      d[3] = cbase[i * 6 + 4];
      d[4] = si;
      labels_out[img * DETS + rank] = (float)(fi / NN + 1);
    }
  }
}

extern "C" void kernel_launch(void* const* d_in, const int* in_sizes, int n_in,
                              void* d_out, int out_size, void* d_ws, size_t ws_size,
                              hipStream_t stream) {
  const float* logits = (const float*)d_in[0];   // [8000, 81]
  const float* reg    = (const float*)d_in[1];   // [8000, 324]
  const float* props  = (const float*)d_in[2];   // [8000, 4]
  // d_in[3] = features, unused (OUTPUT_FEATURE=False)

  float* out = (float*)d_out;                    // dets [8,100,5] then labels [8,100]
  char* ws = (char*)d_ws;
  float*    rowmax   = (float*)(ws);
  float*    rowsum   = (float*)(ws + 32000);
  unsigned* counters = (unsigned*)(ws + 64000);
  float*    cand     = (float*)(ws + 64128);

  softmax_stats<<<(BB * NN + 255) / 256, 256, 0, stream>>>(logits, rowmax, rowsum, counters);
  per_class_nms<<<BB * NC, 256, 0, stream>>>(logits, reg, props, rowmax, rowsum, counters, cand);
  topk_out<<<BB, TK_THREADS, 0, stream>>>(counters, cand, out, out + BB * DETS * 5);
}

// Round 3
// 125.887 us; speedup vs baseline: 65.0650x; 5.8843x over previous
//
#include <hip/hip_runtime.h>
#include <math.h>

#define BB 8
#define NN 1000
#define CC 81
#define NC 80                     // foreground classes
#define IMG_W_M1 1332.0f
#define IMG_H_M1 799.0f
#define SCORE_THRESH 0.05f
#define NMS_THRESH 0.5f
#define DETS 100
#define CAP 8192                  // per-image candidate capacity after NMS
#define DW_CLIP 4.135166556742356f  // log(1000/16) rounded to f32
#define NBINS 4096
#define SELCAP 1024

// ws layout (bytes):
//   [0,      32000)  rowmax  f32[8000]
//   [32000,  64000)  rowsum  f32[8000]
//   [64000,  64032)  counters u32[8]
//   [64128,  64128 + 8*CAP*6*4)  candidates: per image, CAP x {score, x1,y1,x2,y2, flatidx(int)}

__global__ __launch_bounds__(256) void softmax_stats(
    const float* __restrict__ logits, float* __restrict__ rowmax,
    float* __restrict__ rowsum, unsigned* __restrict__ counters) {
  int r = blockIdx.x * 256 + threadIdx.x;
  if (blockIdx.x == 0 && threadIdx.x < BB) counters[threadIdx.x] = 0u;
  if (r >= BB * NN) return;
  const float* l = logits + (size_t)r * CC;
  float m = l[0];
  for (int c = 1; c < CC; ++c) m = fmaxf(m, l[c]);
  float s = 0.0f;
  for (int c = 0; c < CC; ++c) s += expf(l[c] - m);
  rowmax[r] = m;
  rowsum[r] = s;
}

__global__ __launch_bounds__(256) void per_class_nms(
    const float* __restrict__ logits, const float* __restrict__ reg,
    const float* __restrict__ props, const float* __restrict__ rowmax,
    const float* __restrict__ rowsum, unsigned* __restrict__ counters,
    float* __restrict__ cand) {
#pragma clang fp contract(off)
  __shared__ float s_score[NN];
  __shared__ int   s_idx[NN];
  __shared__ float s_sscore[NN];
  __shared__ int   s_sidx[NN];
  __shared__ float s_box[NN * 4];
  __shared__ unsigned char s_keep[NN];
  __shared__ int s_cnt;
  __shared__ unsigned s_base;

  const int img = blockIdx.x / NC;
  const int cls = blockIdx.x % NC + 1;   // foreground class id 1..80
  const int t = threadIdx.x;

  if (t == 0) s_cnt = 0;
  __syncthreads();

  // Phase 1: collect candidates with prob > thresh
  for (int r = t; r < NN; r += 256) {
    int row = img * NN + r;
    float e = expf(logits[(size_t)row * CC + cls] - rowmax[row]);
    float p = e / rowsum[row];          // matches exp(x-max)/sum elementwise div
    if (p > SCORE_THRESH) {
      int pos = atomicAdd(&s_cnt, 1);
      s_score[pos] = p;
      s_idx[pos] = r;
    }
  }
  __syncthreads();
  const int n = s_cnt;

  // Phase 2: rank sort by (score desc, original row asc) == stable argsort(-scores)
  for (int i = t; i < n; i += 256) {
    float si = s_score[i];
    int   ii = s_idx[i];
    int rank = 0;
#pragma unroll 8
    for (int j = 0; j < n; ++j) {
      float sj = s_score[j];
      rank += (int)((sj > si) | ((sj == si) & (s_idx[j] < ii)));
    }
    s_sscore[rank] = si;
    s_sidx[rank] = ii;
  }
  __syncthreads();

  // Phase 3: decode + clip boxes for sorted candidates (BoxCoder.decode, TO_REMOVE=1)
  for (int i = t; i < n; i += 256) {
    int r = s_sidx[i];
    int row = img * NN + r;
    float x1 = props[row * 4 + 0], y1 = props[row * 4 + 1];
    float x2 = props[row * 4 + 2], y2 = props[row * 4 + 3];
    float w = x2 - x1 + 1.0f, h = y2 - y1 + 1.0f;
    float cx = x1 + 0.5f * w,  cy = y1 + 0.5f * h;
    const float* rg = reg + (size_t)row * (CC * 4) + cls * 4;
    float dx = rg[0] / 10.0f, dy = rg[1] / 10.0f;
    float dw = fminf(rg[2] / 5.0f, DW_CLIP);
    float dh = fminf(rg[3] / 5.0f, DW_CLIP);
    float pcx = dx * w + cx, pcy = dy * h + cy;
    float pw = expf(dw) * w, ph = expf(dh) * h;
    float bx1 = pcx - 0.5f * pw;
    float by1 = pcy - 0.5f * ph;
    float bx2 = pcx + 0.5f * pw - 1.0f;
    float by2 = pcy + 0.5f * ph - 1.0f;
    bx1 = fminf(fmaxf(bx1, 0.0f), IMG_W_M1);
    bx2 = fminf(fmaxf(bx2, 0.0f), IMG_W_M1);
    by1 = fminf(fmaxf(by1, 0.0f), IMG_H_M1);
    by2 = fminf(fmaxf(by2, 0.0f), IMG_H_M1);
    s_box[i * 4 + 0] = bx1;
    s_box[i * 4 + 1] = by1;
    s_box[i * 4 + 2] = bx2;
    s_box[i * 4 + 3] = by2;
    s_keep[i] = 1;
  }
  __syncthreads();

  // Phase 4: greedy NMS (torchvision IoU, no +1), identical to reference semantics
  for (int i = 0; i < n; ++i) {
    if (s_keep[i]) {   // uniform branch: all threads read same LDS value
      float ax1 = s_box[i * 4 + 0], ay1 = s_box[i * 4 + 1];
      float ax2 = s_box[i * 4 + 2], ay2 = s_box[i * 4 + 3];
      float areaA = (ax2 - ax1) * (ay2 - ay1);
      for (int j = i + 1 + t; j < n; j += 256) {
        if (!s_keep[j]) continue;
        float bx1 = s_box[j * 4 + 0], by1 = s_box[j * 4 + 1];
        float bx2 = s_box[j * 4 + 2], by2 = s_box[j * 4 + 3];
        float areaB = (bx2 - bx1) * (by2 - by1);
        float wx = fmaxf(fminf(ax2, bx2) - fmaxf(ax1, bx1), 0.0f);
        float wy = fmaxf(fminf(ay2, by2) - fmaxf(ay1, by1), 0.0f);
        float inter = wx * wy;
        float iou = inter / ((areaA + areaB) - inter + 1e-9f);
        if (iou > NMS_THRESH) s_keep[j] = 0;
      }
    }
    __syncthreads();
  }

  // Phase 5: emit survivors — ONE global atomic per block (was ~30, serialized
  // across 80 blocks/image on the same counter), coalesced writes.
  if (t == 0) {
    int tot = 0;
    for (int j = 0; j < n; ++j) tot += s_keep[j];
    s_base = (tot > 0) ? atomicAdd(&counters[img], (unsigned)tot) : 0u;
  }
  __syncthreads();
  for (int i = t; i < n; i += 256) {
    if (s_keep[i]) {
      int pos = 0;
#pragma unroll 4
      for (int j = 0; j < i; ++j) pos += (int)s_keep[j];
      unsigned gpos = s_base + (unsigned)pos;
      if (gpos < CAP) {
        float* c = cand + ((size_t)img * CAP + gpos) * 6;
        c[0] = s_sscore[i];
        c[1] = s_box[i * 4 + 0];
        c[2] = s_box[i * 4 + 1];
        c[3] = s_box[i * 4 + 2];
        c[4] = s_box[i * 4 + 3];
        ((int*)c)[5] = (cls - 1) * NN + s_sidx[i];   // flat idx for tie-break + label
      }
    }
  }
}

#define TK_THREADS 1024

__global__ __launch_bounds__(TK_THREADS) void topk_out(
    const unsigned* __restrict__ counters, const float* __restrict__ cand,
    float* __restrict__ dets_out, float* __restrict__ labels_out) {
#pragma clang fp contract(off)
  __shared__ float s_sc[CAP];
  __shared__ int   s_fl[CAP];
  __shared__ unsigned hist[NBINS];
  __shared__ float s_ssc[SELCAP];
  __shared__ int   s_sfl[SELCAP];
  __shared__ int   s_sci[SELCAP];
  __shared__ int s_m, s_cut;

  const int img = blockIdx.x;
  const int t = threadIdx.x;
  int n = (int)counters[img];
  if (n > CAP) n = CAP;
  const int K = (n < DETS) ? n : DETS;
  const float* cbase = cand + (size_t)img * CAP * 6;

  if (t == 0) { s_m = 0; s_cut = 0; }
  for (int b = t; b < NBINS; b += TK_THREADS) hist[b] = 0u;

  for (int i = t; i < n; i += TK_THREADS) {
    s_sc[i] = cbase[i * 6];
    s_fl[i] = ((const int*)cbase)[i * 6 + 5];
  }
  // Defaults for slots beyond candidate count (ranks 0..min(n,DETS)-1 all get
  // written exactly once below, since ranks are unique).
  for (int k = t; k < DETS; k += TK_THREADS) {
    if (k >= K) {
      float* d = dets_out + (size_t)(img * DETS + k) * 5;
      d[0] = 0.0f; d[1] = 0.0f; d[2] = 0.0f; d[3] = 0.0f; d[4] = 0.0f;
      labels_out[img * DETS + k] = -1.0f;
    }
  }
  __syncthreads();

  // Histogram of scores. bin = floor(score*4096) is monotone non-decreasing in
  // score, so {bin >= T} is upward-closed: it contains the exact global top-K,
  // and within-set ranks equal global ranks (excluded => strictly smaller score).
  for (int i = t; i < n; i += TK_THREADS) {
    float sc = s_sc[i];
    int bin = (int)(sc * (float)NBINS);
    if (bin > NBINS - 1) bin = NBINS - 1;
    atomicAdd(&hist[bin], 1u);
  }
  __syncthreads();

  // Wave 0: find largest cutoff bin T with count(bin >= T) >= K.
  if (t < 64 && K > 0) {
    unsigned s = 0;
#pragma unroll
    for (int b = 0; b < 64; ++b) s += hist[t * 64 + b];
    unsigned suf = s;                       // suffix-inclusive scan over 64 superbins
    for (int d = 1; d < 64; d <<= 1) {
      unsigned o = __shfl_down(suf, d);
      if (t + d < 64) suf += o;
    }
    unsigned long long m1 = __ballot(suf >= (unsigned)K);
    int S = 63 - __clzll(m1);               // largest superbin with suffix >= K
    unsigned tail = 0;
    if (S < 63) tail = __shfl(suf, S + 1);  // S uniform across wave
    unsigned h = hist[S * 64 + t];
    unsigned suf2 = h;
    for (int d = 1; d < 64; d <<= 1) {
      unsigned o = __shfl_down(suf2, d);
      if (t + d < 64) suf2 += o;
    }
    unsigned long long m2 = __ballot((suf2 + tail) >= (unsigned)K);
    int Ls = 63 - __clzll(m2);
    if (t == 0) s_cut = S * 64 + Ls;
  }
  __syncthreads();
  const int cut = s_cut;

  // Select candidates with bin >= cut into compact list.
  if (K > 0) {
    for (int i = t; i < n; i += TK_THREADS) {
      float sc = s_sc[i];
      int bin = (int)(sc * (float)NBINS);
      if (bin > NBINS - 1) bin = NBINS - 1;
      if (bin >= cut) {
        int p = atomicAdd(&s_m, 1);
        if (p < SELCAP) { s_ssc[p] = sc; s_sfl[p] = s_fl[i]; s_sci[p] = i; }
      }
    }
  }
  __syncthreads();
  const int m = s_m;

  if (m <= SELCAP) {
    // Exact rank among selected == global rank. O(m^2), m ~ 100-150.
    for (int i = t; i < m; i += TK_THREADS) {
      float si = s_ssc[i];
      int   fi = s_sfl[i];
      int rank = 0;
#pragma unroll 4
      for (int j = 0; j < m; ++j) {
        float sj = s_ssc[j];
        rank += (int)((sj > si) | ((sj == si) & (s_sfl[j] < fi)));
      }
      if (rank < DETS) {
        int ci = s_sci[i];
        float* d = dets_out + (size_t)(img * DETS + rank) * 5;
        d[0] = cbase[ci * 6 + 1];
        d[1] = cbase[ci * 6 + 2];
        d[2] = cbase[ci * 6 + 3];
        d[3] = cbase[ci * 6 + 4];
        d[4] = si;
        labels_out[img * DETS + rank] = (float)(fi / NN + 1);
      }
    }
  } else {
    // Fallback (mass-tie pathology): full O(n^2) rank, provably correct.
    for (int i = t; i < n; i += TK_THREADS) {
      float si = s_sc[i];
      int   fi = s_fl[i];
      int rank = 0;
#pragma unroll 8
      for (int j = 0; j < n; ++j) {
        float sj = s_sc[j];
        rank += (int)((sj > si) | ((sj == si) & (s_fl[j] < fi)));
      }
      if (rank < DETS) {
        float* d = dets_out + (size_t)(img * DETS + rank) * 5;
        d[0] = cbase[i * 6 + 1];
        d[1] = cbase[i * 6 + 2];
        d[2] = cbase[i * 6 + 3];
        d[3] = cbase[i * 6 + 4];
        d[4] = si;
        labels_out[img * DETS + rank] = (float)(fi / NN + 1);
      }
    }
  }
}

extern "C" void kernel_launch(void* const* d_in, const int* in_sizes, int n_in,
                              void* d_out, int out_size, void* d_ws, size_t ws_size,
                              hipStream_t stream) {
  const float* logits = (const float*)d_in[0];   // [8000, 81]
  const float* reg    = (const float*)d_in[1];   // [8000, 324]
  const float* props  = (const float*)d_in[2];   // [8000, 4]
  // d_in[3] = features, unused (OUTPUT_FEATURE=False)

  float* out = (float*)d_out;                    // dets [8,100,5] then labels [8,100]
  char* ws = (char*)d_ws;
  float*    rowmax   = (float*)(ws);
  float*    rowsum   = (float*)(ws + 32000);
  unsigned* counters = (unsigned*)(ws + 64000);
  float*    cand     = (float*)(ws + 64128);

  softmax_stats<<<(BB * NN + 255) / 256, 256, 0, stream>>>(logits, rowmax, rowsum, counters);
  per_class_nms<<<BB * NC, 256, 0, stream>>>(logits, reg, props, rowmax, rowsum, counters, cand);
  topk_out<<<BB, TK_THREADS, 0, stream>>>(counters, cand, out, out + BB * DETS * 5);
}